// Round 1
// baseline (3150.864 us; speedup 1.0000x reference)
//
#include <hip/hip_runtime.h>
#include <cmath>
#include <cstddef>

#define N_NODES 50000
#define E_EDGES 640000
#define HDIM 128
#define COUT 64
#define NLAYERS 16
#define ALPHA_C 0.1f
#define LAMDA_C 0.5f

// ---------------- setup kernels ----------------

__global__ __launch_bounds__(256) void k_deg_init(float* deg) {
    int i = blockIdx.x * 256 + threadIdx.x;
    if (i < N_NODES) deg[i] = 1.0f;   // self-loop weight
}

__global__ __launch_bounds__(256) void k_deg_acc(const int* __restrict__ ei,
                                                 const float* __restrict__ ew,
                                                 float* deg) {
    int e = blockIdx.x * 256 + threadIdx.x;
    if (e < E_EDGES) atomicAdd(&deg[ei[e]], ew[e]);
}

__global__ __launch_bounds__(256) void k_dinv(float* deg) {
    int i = blockIdx.x * 256 + threadIdx.x;
    if (i < N_NODES) deg[i] = 1.0f / sqrtf(deg[i]);  // deg >= 1 always
}

__global__ __launch_bounds__(256) void k_hist(const int* __restrict__ ei, int* cnt) {
    int e = blockIdx.x * 256 + threadIdx.x;
    if (e < E_EDGES) atomicAdd(&cnt[ei[E_EDGES + e]], 1);
}

__global__ __launch_bounds__(1024) void k_scan(const int* __restrict__ cnt, int* ptr) {
    __shared__ int sums[1024];
    const int tid = threadIdx.x;
    const int CH = (N_NODES + 1023) / 1024;
    int b = tid * CH;
    int e = min(b + CH, N_NODES);
    int s = 0;
    for (int i = b; i < e; ++i) s += cnt[i];
    sums[tid] = s;
    __syncthreads();
    for (int off = 1; off < 1024; off <<= 1) {
        int v = sums[tid];
        int u = (tid >= off) ? sums[tid - off] : 0;
        __syncthreads();
        sums[tid] = v + u;
        __syncthreads();
    }
    int run = (tid == 0) ? 0 : sums[tid - 1];
    for (int i = b; i < e; ++i) { ptr[i] = run; run += cnt[i]; }
    if (tid == 1023) ptr[N_NODES] = sums[1023];
}

__global__ __launch_bounds__(256) void k_scatter(const int* __restrict__ ei,
                                                 const float* __restrict__ ew,
                                                 const float* __restrict__ dinv,
                                                 const int* __restrict__ ptr,
                                                 int* fill, int* srow, float* snorm) {
    int e = blockIdx.x * 256 + threadIdx.x;
    if (e >= E_EDGES) return;
    int r = ei[e];
    int c = ei[E_EDGES + e];
    int pos = ptr[c] + atomicAdd(&fill[c], 1);
    srow[pos] = r;
    snorm[pos] = dinv[r] * ew[e] * dinv[c];
}

// ---------------- GEMM: [M x 128] @ [128 x BN] ----------------
// EPI 0: out = relu(acc + bias[c]); dual store (Out, Out2)
// EPI 1: out = beta*acc + cscale*Cin[r][c]
// EPI 2: out = acc + bias[c]
template <int BN, int TN, int EPI>
__global__ __launch_bounds__(256) void gemm128(
    const float* __restrict__ A, const float* __restrict__ W,
    const float* __restrict__ Cin, const float* __restrict__ bias,
    float* __restrict__ Out, float* __restrict__ Out2,
    int M, float beta, float cscale) {
    constexpr int BM = 64, KB = 16, TM = 8;
    __shared__ float As[KB][BM];
    __shared__ float Bs[KB][BN];
    const int tid = threadIdx.x;
    const int row0 = blockIdx.x * BM;
    const int tr = (tid >> 5) * TM;
    const int tc = (tid & 31) * TN;

    float acc[TM][TN];
#pragma unroll
    for (int m = 0; m < TM; ++m)
#pragma unroll
        for (int n = 0; n < TN; ++n) acc[m][n] = 0.f;

    const int ar = tid >> 2;          // 0..63
    const int ak = (tid & 3) << 2;    // 0,4,8,12
    constexpr int BPT = (KB * BN / 4) / 256;  // float4 per thread for B

    for (int k0 = 0; k0 < 128; k0 += KB) {
        float4 av = make_float4(0.f, 0.f, 0.f, 0.f);
        int grow = row0 + ar;
        if (grow < M) av = *(const float4*)&A[(size_t)grow * HDIM + k0 + ak];
        float4 bv[BPT];
#pragma unroll
        for (int j = 0; j < BPT; ++j) {
            int idx = tid + j * 256;
            int kr = idx / (BN / 4);
            int c4 = (idx % (BN / 4)) * 4;
            bv[j] = *(const float4*)&W[(size_t)(k0 + kr) * BN + c4];
        }
        __syncthreads();
        As[ak + 0][ar] = av.x;
        As[ak + 1][ar] = av.y;
        As[ak + 2][ar] = av.z;
        As[ak + 3][ar] = av.w;
#pragma unroll
        for (int j = 0; j < BPT; ++j) {
            int idx = tid + j * 256;
            int kr = idx / (BN / 4);
            int c4 = (idx % (BN / 4)) * 4;
            *(float4*)&Bs[kr][c4] = bv[j];
        }
        __syncthreads();
#pragma unroll
        for (int kk = 0; kk < KB; ++kk) {
            float a[TM];
            *(float4*)&a[0] = *(const float4*)&As[kk][tr];
            *(float4*)&a[4] = *(const float4*)&As[kk][tr + 4];
            float b[TN];
            if constexpr (TN == 4) {
                *(float4*)&b[0] = *(const float4*)&Bs[kk][tc];
            } else {
                *(float2*)&b[0] = *(const float2*)&Bs[kk][tc];
            }
#pragma unroll
            for (int m = 0; m < TM; ++m)
#pragma unroll
                for (int n = 0; n < TN; ++n)
                    acc[m][n] = fmaf(a[m], b[n], acc[m][n]);
        }
    }

#pragma unroll
    for (int m = 0; m < TM; ++m) {
        int grow = row0 + tr + m;
        if (grow < M) {
            float o[TN];
#pragma unroll
            for (int n = 0; n < TN; ++n) {
                float v = acc[m][n];
                if constexpr (EPI == 0) {
                    v = fmaxf(v + bias[tc + n], 0.f);
                } else if constexpr (EPI == 1) {
                    v = beta * v + cscale * Cin[(size_t)grow * BN + tc + n];
                } else {
                    v = v + bias[tc + n];
                }
                o[n] = v;
            }
            if constexpr (TN == 4) {
                *(float4*)&Out[(size_t)grow * BN + tc] = *(float4*)&o[0];
                if constexpr (EPI == 0)
                    *(float4*)&Out2[(size_t)grow * BN + tc] = *(float4*)&o[0];
            } else {
                *(float2*)&Out[(size_t)grow * BN + tc] = *(float2*)&o[0];
            }
        }
    }
}

// ---------------- aggregation: wave per node ----------------
// h_new[v] = relu( sum_e norm[e]*support[srow[e]] + dinv[v]^2*support[v] + initial[v] )
__global__ __launch_bounds__(256) void k_aggregate(
    const float* __restrict__ support, const float* __restrict__ initial,
    const float* __restrict__ dinv, const int* __restrict__ ptr,
    const int* __restrict__ srow, const float* __restrict__ snorm,
    float* __restrict__ hout) {
    int v = blockIdx.x * 4 + (threadIdx.x >> 6);
    int lane = threadIdx.x & 63;
    if (v >= N_NODES) return;
    int beg = ptr[v], end = ptr[v + 1];
    float dv = dinv[v];
    float2 s0 = *(const float2*)&support[(size_t)v * HDIM + lane * 2];
    float accx = dv * dv * s0.x;
    float accy = dv * dv * s0.y;
    for (int e = beg; e < end; ++e) {
        int r = srow[e];
        float nm = snorm[e];
        float2 sv = *(const float2*)&support[(size_t)r * HDIM + lane * 2];
        accx = fmaf(nm, sv.x, accx);
        accy = fmaf(nm, sv.y, accy);
    }
    float2 ini = *(const float2*)&initial[(size_t)v * HDIM + lane * 2];
    float2 o;
    o.x = fmaxf(accx + ini.x, 0.f);
    o.y = fmaxf(accy + ini.y, 0.f);
    *(float2*)&hout[(size_t)v * HDIM + lane * 2] = o;
}

// ---------------- log_softmax, in place, wave per row (64 cols) ----------------
__global__ __launch_bounds__(256) void k_logsoftmax(float* __restrict__ out) {
    int r = blockIdx.x * 4 + (threadIdx.x >> 6);
    int lane = threadIdx.x & 63;
    if (r >= N_NODES) return;
    float z = out[(size_t)r * COUT + lane];
    float m = z;
    for (int off = 32; off; off >>= 1) m = fmaxf(m, __shfl_xor(m, off));
    float s = expf(z - m);
    for (int off = 32; off; off >>= 1) s += __shfl_xor(s, off);
    out[(size_t)r * COUT + lane] = z - m - logf(s);
}

// ---------------- launch ----------------

extern "C" void kernel_launch(void* const* d_in, const int* in_sizes, int n_in,
                              void* d_out, int out_size, void* d_ws, size_t ws_size,
                              hipStream_t stream) {
    const float* x = (const float*)d_in[0];
    const int* ei = (const int*)d_in[1];
    const float* ew = (const float*)d_in[2];
    const float* w_in = (const float*)d_in[3];
    const float* b_in = (const float*)d_in[4];
    const float* ws1 = (const float*)d_in[5];
    const float* ws2 = (const float*)d_in[6];
    const float* w_out = (const float*)d_in[7];
    const float* b_out = (const float*)d_in[8];
    float* out = (float*)d_out;

    char* p = (char*)d_ws;
    auto alloc = [&](size_t bytes) {
        void* r = (void*)p;
        p += (bytes + 255) & ~(size_t)255;
        return r;
    };
    float* dinv = (float*)alloc(N_NODES * 4);            // deg -> dinv in place
    int* cnt = (int*)alloc(N_NODES * 4);
    int* ptr = (int*)alloc((N_NODES + 1) * 4);
    int* fill = (int*)alloc(N_NODES * 4);
    int* srow = (int*)alloc(E_EDGES * 4);
    float* snorm = (float*)alloc(E_EDGES * 4);
    float* h = (float*)alloc((size_t)N_NODES * HDIM * 4);
    float* h0 = (float*)alloc((size_t)N_NODES * HDIM * 4);
    float* support = (float*)alloc((size_t)N_NODES * HDIM * 4);
    // 'initial' shares the h buffer: h is dead after the support GEMM each layer.

    hipMemsetAsync(cnt, 0, N_NODES * 4, stream);
    hipMemsetAsync(fill, 0, N_NODES * 4, stream);

    int gn = (N_NODES + 255) / 256;
    int ge = (E_EDGES + 255) / 256;
    k_deg_init<<<gn, 256, 0, stream>>>(dinv);
    k_deg_acc<<<ge, 256, 0, stream>>>(ei, ew, dinv);
    k_dinv<<<gn, 256, 0, stream>>>(dinv);
    k_hist<<<ge, 256, 0, stream>>>(ei, cnt);
    k_scan<<<1, 1024, 0, stream>>>(cnt, ptr);
    k_scatter<<<ge, 256, 0, stream>>>(ei, ew, dinv, ptr, fill, srow, snorm);

    const int gb = (N_NODES + 63) / 64;  // 782
    // h = relu(x @ w_in + b_in); also h0 = h
    gemm128<128, 4, 0><<<gb, 256, 0, stream>>>(x, w_in, nullptr, b_in, h, h0,
                                               N_NODES, 0.f, 0.f);

    for (int i = 0; i < NLAYERS; ++i) {
        float beta = (float)log((double)LAMDA_C / (i + 1) + 1.0);
        float c1 = (1.f - beta) * (1.f - ALPHA_C);
        float c2 = (1.f - beta) * ALPHA_C;
        // support = c1*h + beta*(h @ ws1[i])
        gemm128<128, 4, 1><<<gb, 256, 0, stream>>>(
            h, ws1 + (size_t)i * HDIM * HDIM, h, nullptr, support, nullptr,
            N_NODES, beta, c1);
        // initial = c2*h0 + beta*(h0 @ ws2[i])  -> stored into h (dead now)
        gemm128<128, 4, 1><<<gb, 256, 0, stream>>>(
            h0, ws2 + (size_t)i * HDIM * HDIM, h0, nullptr, h, nullptr,
            N_NODES, beta, c2);
        // h = relu(agg + initial)
        k_aggregate<<<(N_NODES + 3) / 4, 256, 0, stream>>>(support, h, dinv, ptr,
                                                           srow, snorm, h);
    }

    // logits = h @ w_out + b_out  (written straight to d_out)
    gemm128<64, 2, 2><<<gb, 256, 0, stream>>>(h, w_out, nullptr, b_out, out,
                                              nullptr, N_NODES, 0.f, 0.f);
    k_logsoftmax<<<(N_NODES + 3) / 4, 256, 0, stream>>>(out);
}

// Round 2
// 1277.227 us; speedup vs baseline: 2.4670x; 2.4670x over previous
//
#include <hip/hip_runtime.h>
#include <cmath>
#include <cstddef>

#define N_NODES 50000
#define N_PAD   50048
#define E_EDGES 640000
#define HDIM 128
#define COUT 64
#define NLAYERS 16
#define ALPHA_C 0.1f
#define LAMDA_C 0.5f
#define SCAN_BLKS 196   // ceil(50000/256)

typedef __attribute__((ext_vector_type(8))) short short8;
typedef __attribute__((ext_vector_type(4))) float f32x4;

__device__ __forceinline__ float bf2f(ushort u) {
    union { unsigned u; float f; } x; x.u = ((unsigned)u) << 16; return x.f;
}
__device__ __forceinline__ ushort f2bf(float f) {
    union { float f; unsigned u; } x; x.f = f;
    unsigned r = x.u + 0x7FFFu + ((x.u >> 16) & 1u);
    return (ushort)(r >> 16);
}

// ---------------- graph setup ----------------

__global__ __launch_bounds__(256) void k_init(float* deg, int* cnt, int* fill) {
    int i = blockIdx.x * 256 + threadIdx.x;
    if (i < N_NODES) { deg[i] = 1.0f; cnt[i] = 0; fill[i] = 0; }
}

__global__ __launch_bounds__(256) void k_edge(const int* __restrict__ ei,
                                              const float* __restrict__ ew,
                                              float* deg, int* cnt) {
    int e = blockIdx.x * 256 + threadIdx.x;
    if (e < E_EDGES) {
        atomicAdd(&deg[ei[e]], ew[e]);
        atomicAdd(&cnt[ei[E_EDGES + e]], 1);
    }
}

__global__ __launch_bounds__(256) void k_dinv(float* deg) {
    int i = blockIdx.x * 256 + threadIdx.x;
    if (i < N_NODES) deg[i] = 1.0f / sqrtf(deg[i]);
}

__global__ __launch_bounds__(256) void k_scan1(const int* __restrict__ cnt,
                                               int* ptrTmp, int* bsum) {
    __shared__ int s[256];
    int t = threadIdx.x;
    int i = blockIdx.x * 256 + t;
    int v = (i < N_NODES) ? cnt[i] : 0;
    s[t] = v; __syncthreads();
    for (int off = 1; off < 256; off <<= 1) {
        int x = s[t]; int y = (t >= off) ? s[t - off] : 0;
        __syncthreads();
        s[t] = x + y; __syncthreads();
    }
    if (i < N_NODES) ptrTmp[i] = s[t] - v;
    if (t == 255) bsum[blockIdx.x] = s[255];
}

__global__ __launch_bounds__(256) void k_scan2(const int* __restrict__ bsum, int* boff) {
    __shared__ int s[256];
    int t = threadIdx.x;
    int v = (t < SCAN_BLKS) ? bsum[t] : 0;
    s[t] = v; __syncthreads();
    for (int off = 1; off < 256; off <<= 1) {
        int x = s[t]; int y = (t >= off) ? s[t - off] : 0;
        __syncthreads();
        s[t] = x + y; __syncthreads();
    }
    if (t < SCAN_BLKS) boff[t] = s[t] - v;
}

__global__ __launch_bounds__(256) void k_scan3(const int* __restrict__ ptrTmp,
                                               const int* __restrict__ boff, int* ptr) {
    int i = blockIdx.x * 256 + threadIdx.x;
    if (i < N_NODES) ptr[i] = ptrTmp[i] + boff[blockIdx.x];
    if (i == 0) ptr[N_NODES] = E_EDGES + 0;
}

__global__ __launch_bounds__(256) void k_scatter(const int* __restrict__ ei,
                                                 const float* __restrict__ ew,
                                                 const float* __restrict__ dinv,
                                                 const int* __restrict__ ptr,
                                                 int* fill, int* srow, float* snorm) {
    int e = blockIdx.x * 256 + threadIdx.x;
    if (e >= E_EDGES) return;
    int r = ei[e];
    int c = ei[E_EDGES + e];
    int pos = ptr[c] + atomicAdd(&fill[c], 1);
    srow[pos] = r;
    snorm[pos] = dinv[r] * ew[e] * dinv[c];
}

// ---------------- weight convert + transpose (f32 [R][C] -> bf16 [C][R]) ----------------

__global__ __launch_bounds__(256) void k_convert_w(
    const float* __restrict__ w_in, const float* __restrict__ ws1,
    const float* __restrict__ ws2, const float* __restrict__ w_out,
    ushort* wt_in, ushort* wt1, ushort* wt2, ushort* wt_out) {
    __shared__ ushort tile[128][130];
    int b = blockIdx.x;
    const float* src; ushort* dst; int R = 128, C = 128;
    if (b == 0)       { src = w_in;                 dst = wt_in; }
    else if (b <= 16) { src = ws1 + (b - 1) * 16384;  dst = wt1 + (b - 1) * 16384; }
    else if (b <= 32) { src = ws2 + (b - 17) * 16384; dst = wt2 + (b - 17) * 16384; }
    else              { src = w_out;                dst = wt_out; C = 64; }
    for (int idx = threadIdx.x; idx < R * C; idx += 256) {
        int k = idx / C, n = idx % C;
        tile[k][n] = f2bf(src[idx]);
    }
    __syncthreads();
    for (int idx = threadIdx.x; idx < R * C; idx += 256) {
        int n = idx / R, k = idx % R;
        dst[idx] = tile[k][n];
    }
}

// ---------------- x convert (f32 -> bf16, zero-pad rows) ----------------

__global__ __launch_bounds__(256) void k_convert_x(const float* __restrict__ x,
                                                   ushort* __restrict__ xb) {
    int c8 = blockIdx.x * 256 + threadIdx.x;   // 8-elem chunk
    if (c8 >= N_PAD * (HDIM / 8)) return;
    int row = c8 / (HDIM / 8);
    short8 o;
    if (row < N_NODES) {
        const float4 f0 = *(const float4*)&x[(size_t)c8 * 8];
        const float4 f1 = *(const float4*)&x[(size_t)c8 * 8 + 4];
        o[0] = (short)f2bf(f0.x); o[1] = (short)f2bf(f0.y);
        o[2] = (short)f2bf(f0.z); o[3] = (short)f2bf(f0.w);
        o[4] = (short)f2bf(f1.x); o[5] = (short)f2bf(f1.y);
        o[6] = (short)f2bf(f1.z); o[7] = (short)f2bf(f1.w);
    } else {
        o = (short8){0, 0, 0, 0, 0, 0, 0, 0};
    }
    *(short8*)&xb[(size_t)c8 * 8] = o;
}

// ---------------- input GEMM: h = h0 = relu(xb @ W + bias) ----------------
// A [N_PAD][128] bf16, W transposed [128][128] bf16

__global__ __launch_bounds__(256) void k_gemm_in(
    const ushort* __restrict__ A, const ushort* __restrict__ W,
    const float* __restrict__ bias, ushort* __restrict__ O0, ushort* __restrict__ O1) {
    const int tid = threadIdx.x;
    const int wid = tid >> 6, l = tid & 63;
    const int wm = wid >> 1, wn = wid & 1;
    const int lr = l & 15, lk = l >> 4;
    const int row0 = blockIdx.x * 128 + wm * 64;
    const int col0 = wn * 64;

    short8 a[4][4], b[4][4];
#pragma unroll
    for (int m = 0; m < 4; ++m)
#pragma unroll
        for (int k = 0; k < 4; ++k)
            a[m][k] = *(const short8*)&A[(size_t)(row0 + m * 16 + lr) * HDIM + k * 32 + lk * 8];
#pragma unroll
    for (int n = 0; n < 4; ++n)
#pragma unroll
        for (int k = 0; k < 4; ++k)
            b[n][k] = *(const short8*)&W[(size_t)(col0 + n * 16 + lr) * HDIM + k * 32 + lk * 8];

    f32x4 acc[4][4];
#pragma unroll
    for (int m = 0; m < 4; ++m)
#pragma unroll
        for (int n = 0; n < 4; ++n) acc[m][n] = (f32x4){0.f, 0.f, 0.f, 0.f};
#pragma unroll
    for (int k = 0; k < 4; ++k)
#pragma unroll
        for (int m = 0; m < 4; ++m)
#pragma unroll
            for (int n = 0; n < 4; ++n)
                acc[m][n] = __builtin_amdgcn_mfma_f32_16x16x32_bf16(a[m][k], b[n][k], acc[m][n], 0, 0, 0);

    float bv[4];
#pragma unroll
    for (int n = 0; n < 4; ++n) bv[n] = bias[col0 + n * 16 + lr];
#pragma unroll
    for (int m = 0; m < 4; ++m) {
        const int rb = row0 + m * 16 + lk * 4;
#pragma unroll
        for (int j = 0; j < 4; ++j) {
            const size_t ro = (size_t)(rb + j) * HDIM;
#pragma unroll
            for (int n = 0; n < 4; ++n) {
                const int c = col0 + n * 16 + lr;
                float v = fmaxf(acc[m][n][j] + bv[n], 0.f);
                ushort u = f2bf(v);
                O0[ro + c] = u;
                O1[ro + c] = u;
            }
        }
    }
}

// ---------------- fused layer GEMMs (grid.y: 0 -> support, 1 -> initial) ----------------
// Out = beta*(A @ W) + cs*A

__global__ __launch_bounds__(256) void k_gemm2(
    const ushort* __restrict__ A0, const ushort* __restrict__ A1,
    const ushort* __restrict__ W0, const ushort* __restrict__ W1,
    ushort* __restrict__ O0, ushort* __restrict__ O1,
    float beta, float s0, float s1) {
    const int y = blockIdx.y;
    const ushort* __restrict__ A = y ? A1 : A0;
    const ushort* __restrict__ W = y ? W1 : W0;
    ushort* __restrict__ O = y ? O1 : O0;
    const float cs = y ? s1 : s0;
    const int tid = threadIdx.x;
    const int wid = tid >> 6, l = tid & 63;
    const int wm = wid >> 1, wn = wid & 1;
    const int lr = l & 15, lk = l >> 4;
    const int row0 = blockIdx.x * 128 + wm * 64;
    const int col0 = wn * 64;

    short8 a[4][4], b[4][4];
#pragma unroll
    for (int m = 0; m < 4; ++m)
#pragma unroll
        for (int k = 0; k < 4; ++k)
            a[m][k] = *(const short8*)&A[(size_t)(row0 + m * 16 + lr) * HDIM + k * 32 + lk * 8];
#pragma unroll
    for (int n = 0; n < 4; ++n)
#pragma unroll
        for (int k = 0; k < 4; ++k)
            b[n][k] = *(const short8*)&W[(size_t)(col0 + n * 16 + lr) * HDIM + k * 32 + lk * 8];

    f32x4 acc[4][4];
#pragma unroll
    for (int m = 0; m < 4; ++m)
#pragma unroll
        for (int n = 0; n < 4; ++n) acc[m][n] = (f32x4){0.f, 0.f, 0.f, 0.f};
#pragma unroll
    for (int k = 0; k < 4; ++k)
#pragma unroll
        for (int m = 0; m < 4; ++m)
#pragma unroll
            for (int n = 0; n < 4; ++n)
                acc[m][n] = __builtin_amdgcn_mfma_f32_16x16x32_bf16(a[m][k], b[n][k], acc[m][n], 0, 0, 0);

#pragma unroll
    for (int m = 0; m < 4; ++m) {
        const int rb = row0 + m * 16 + lk * 4;
#pragma unroll
        for (int j = 0; j < 4; ++j) {
            const size_t ro = (size_t)(rb + j) * HDIM;
#pragma unroll
            for (int n = 0; n < 4; ++n) {
                const int c = col0 + n * 16 + lr;
                float v = beta * acc[m][n][j] + cs * bf2f(A[ro + c]);
                O[ro + c] = f2bf(v);
            }
        }
    }
}

// ---------------- aggregation: wave per node, bf16 gathers ----------------

__global__ __launch_bounds__(256) void k_aggregate(
    const ushort* __restrict__ support, const ushort* __restrict__ initial,
    const float* __restrict__ dinv, const int* __restrict__ ptr,
    const int* __restrict__ srow, const float* __restrict__ snorm,
    ushort* __restrict__ hout) {
    int v = blockIdx.x * 4 + (threadIdx.x >> 6);
    int l = threadIdx.x & 63;
    if (v >= N_NODES) return;
    int beg = ptr[v], end = ptr[v + 1];
    float dv = dinv[v];
    ushort2 s0 = *(const ushort2*)&support[(size_t)v * HDIM + l * 2];
    float accx = dv * dv * bf2f(s0.x);
    float accy = dv * dv * bf2f(s0.y);
    for (int base = beg; base < end; base += 64) {
        int cnt = min(64, end - base);
        int rB = 0; float nB = 0.f;
        if (base + l < end) { rB = srow[base + l]; nB = snorm[base + l]; }
        for (int j = 0; j < cnt; ++j) {
            int rr = __shfl(rB, j);
            float nn = __shfl(nB, j);
            ushort2 sv = *(const ushort2*)&support[(size_t)rr * HDIM + l * 2];
            accx = fmaf(nn, bf2f(sv.x), accx);
            accy = fmaf(nn, bf2f(sv.y), accy);
        }
    }
    ushort2 ini = *(const ushort2*)&initial[(size_t)v * HDIM + l * 2];
    ushort2 o;
    o.x = f2bf(fmaxf(accx + bf2f(ini.x), 0.f));
    o.y = f2bf(fmaxf(accy + bf2f(ini.y), 0.f));
    *(ushort2*)&hout[(size_t)v * HDIM + l * 2] = o;
}

// ---------------- output GEMM + fused bias + log_softmax ----------------
// A [N_PAD][128] bf16, W transposed [64][128] bf16, out f32 [N][64]

__global__ __launch_bounds__(256) void k_gemm_out(
    const ushort* __restrict__ A, const ushort* __restrict__ W,
    const float* __restrict__ bias, float* __restrict__ out) {
    const int tid = threadIdx.x;
    const int wid = tid >> 6, l = tid & 63;
    const int lr = l & 15, lk = l >> 4;
    const int row0 = blockIdx.x * 128 + wid * 32;

    short8 a[2][4], b[4][4];
#pragma unroll
    for (int m = 0; m < 2; ++m)
#pragma unroll
        for (int k = 0; k < 4; ++k)
            a[m][k] = *(const short8*)&A[(size_t)(row0 + m * 16 + lr) * HDIM + k * 32 + lk * 8];
#pragma unroll
    for (int n = 0; n < 4; ++n)
#pragma unroll
        for (int k = 0; k < 4; ++k)
            b[n][k] = *(const short8*)&W[(size_t)(n * 16 + lr) * HDIM + k * 32 + lk * 8];

    f32x4 acc[2][4];
#pragma unroll
    for (int m = 0; m < 2; ++m)
#pragma unroll
        for (int n = 0; n < 4; ++n) acc[m][n] = (f32x4){0.f, 0.f, 0.f, 0.f};
#pragma unroll
    for (int k = 0; k < 4; ++k)
#pragma unroll
        for (int m = 0; m < 2; ++m)
#pragma unroll
            for (int n = 0; n < 4; ++n)
                acc[m][n] = __builtin_amdgcn_mfma_f32_16x16x32_bf16(a[m][k], b[n][k], acc[m][n], 0, 0, 0);

    float bv[4];
#pragma unroll
    for (int n = 0; n < 4; ++n) bv[n] = bias[n * 16 + lr];

#pragma unroll
    for (int m = 0; m < 2; ++m) {
#pragma unroll
        for (int j = 0; j < 4; ++j) {
            float z[4];
#pragma unroll
            for (int n = 0; n < 4; ++n) z[n] = acc[m][n][j] + bv[n];
            float mx = fmaxf(fmaxf(z[0], z[1]), fmaxf(z[2], z[3]));
#pragma unroll
            for (int off = 1; off < 16; off <<= 1) mx = fmaxf(mx, __shfl_xor(mx, off));
            float s = 0.f;
#pragma unroll
            for (int n = 0; n < 4; ++n) s += expf(z[n] - mx);
#pragma unroll
            for (int off = 1; off < 16; off <<= 1) s += __shfl_xor(s, off);
            float lg = mx + logf(s);
            int r = row0 + m * 16 + lk * 4 + j;
            if (r < N_NODES) {
#pragma unroll
                for (int n = 0; n < 4; ++n)
                    out[(size_t)r * COUT + n * 16 + lr] = z[n] - lg;
            }
        }
    }
}

// ---------------- launch ----------------

extern "C" void kernel_launch(void* const* d_in, const int* in_sizes, int n_in,
                              void* d_out, int out_size, void* d_ws, size_t ws_size,
                              hipStream_t stream) {
    const float* x = (const float*)d_in[0];
    const int* ei = (const int*)d_in[1];
    const float* ew = (const float*)d_in[2];
    const float* w_in = (const float*)d_in[3];
    const float* b_in = (const float*)d_in[4];
    const float* ws1 = (const float*)d_in[5];
    const float* ws2 = (const float*)d_in[6];
    const float* w_out = (const float*)d_in[7];
    const float* b_out = (const float*)d_in[8];
    float* out = (float*)d_out;

    char* p = (char*)d_ws;
    auto alloc = [&](size_t bytes) {
        void* r = (void*)p;
        p += (bytes + 255) & ~(size_t)255;
        return r;
    };
    float* dinv = (float*)alloc(N_NODES * 4);
    int* cnt = (int*)alloc(N_NODES * 4);
    int* ptrTmp = (int*)alloc(N_NODES * 4);
    int* bsum = (int*)alloc(256 * 4);
    int* boff = (int*)alloc(256 * 4);
    int* ptr = (int*)alloc((N_NODES + 1) * 4);
    int* fill = (int*)alloc(N_NODES * 4);
    int* srow = (int*)alloc(E_EDGES * 4);
    float* snorm = (float*)alloc(E_EDGES * 4);
    ushort* xb = (ushort*)alloc((size_t)N_PAD * HDIM * 2);
    ushort* h = (ushort*)alloc((size_t)N_PAD * HDIM * 2);
    ushort* h0 = (ushort*)alloc((size_t)N_PAD * HDIM * 2);
    ushort* support = (ushort*)alloc((size_t)N_PAD * HDIM * 2);
    ushort* init = (ushort*)alloc((size_t)N_PAD * HDIM * 2);
    ushort* wt_in = (ushort*)alloc(128 * 128 * 2);
    ushort* wt1 = (ushort*)alloc((size_t)NLAYERS * 128 * 128 * 2);
    ushort* wt2 = (ushort*)alloc((size_t)NLAYERS * 128 * 128 * 2);
    ushort* wt_out = (ushort*)alloc(64 * 128 * 2);

    const int ge = (E_EDGES + 255) / 256;
    k_init<<<SCAN_BLKS, 256, 0, stream>>>(dinv, cnt, fill);
    k_edge<<<ge, 256, 0, stream>>>(ei, ew, dinv, cnt);
    k_dinv<<<SCAN_BLKS, 256, 0, stream>>>(dinv);
    k_scan1<<<SCAN_BLKS, 256, 0, stream>>>(cnt, ptrTmp, bsum);
    k_scan2<<<1, 256, 0, stream>>>(bsum, boff);
    k_scan3<<<SCAN_BLKS, 256, 0, stream>>>(ptrTmp, boff, ptr);
    k_scatter<<<ge, 256, 0, stream>>>(ei, ew, dinv, ptr, fill, srow, snorm);

    k_convert_w<<<34, 256, 0, stream>>>(w_in, ws1, ws2, w_out, wt_in, wt1, wt2, wt_out);
    k_convert_x<<<(N_PAD * (HDIM / 8) + 255) / 256, 256, 0, stream>>>(x, xb);

    const int gb = N_PAD / 128;  // 391
    k_gemm_in<<<gb, 256, 0, stream>>>(xb, wt_in, b_in, h, h0);

    for (int i = 0; i < NLAYERS; ++i) {
        float beta = (float)log((double)LAMDA_C / (i + 1) + 1.0);
        float c1 = (1.f - beta) * (1.f - ALPHA_C);
        float c2 = (1.f - beta) * ALPHA_C;
        k_gemm2<<<dim3(gb, 2), 256, 0, stream>>>(h, h0,
                                                 wt1 + (size_t)i * 16384,
                                                 wt2 + (size_t)i * 16384,
                                                 support, init, beta, c1, c2);
        k_aggregate<<<(N_NODES + 3) / 4, 256, 0, stream>>>(support, init, dinv, ptr,
                                                           srow, snorm, h);
    }

    k_gemm_out<<<gb, 256, 0, stream>>>(h, wt_out, b_out, out);
}

// Round 3
// 964.092 us; speedup vs baseline: 3.2682x; 1.3248x over previous
//
#include <hip/hip_runtime.h>
#include <cmath>
#include <cstddef>

#define N_NODES 50000
#define N_PAD   50048
#define E_EDGES 640000
#define HDIM 128
#define COUT 64
#define NLAYERS 16
#define ALPHA_C 0.1f
#define LAMDA_C 0.5f
#define SCAN_BLKS 196   // ceil(50000/256)

typedef __attribute__((ext_vector_type(8))) short short8;
typedef __attribute__((ext_vector_type(4))) float f32x4;

__device__ __forceinline__ float bf2f(ushort u) {
    union { unsigned u; float f; } x; x.u = ((unsigned)u) << 16; return x.f;
}
__device__ __forceinline__ ushort f2bf(float f) {
    union { float f; unsigned u; } x; x.f = f;
    unsigned r = x.u + 0x7FFFu + ((x.u >> 16) & 1u);
    return (ushort)(r >> 16);
}

// ---------------- graph setup ----------------

__global__ __launch_bounds__(256) void k_init(float* deg, int* cnt, int* fill) {
    int i = blockIdx.x * 256 + threadIdx.x;
    if (i < N_NODES) { deg[i] = 1.0f; cnt[i] = 0; fill[i] = 0; }
}

// 4 edges per thread: 8 independent atomics in flight
__global__ __launch_bounds__(256) void k_edge(const int* __restrict__ ei,
                                              const float* __restrict__ ew,
                                              float* deg, int* cnt) {
    int t = blockIdx.x * 256 + threadIdx.x;
    int e0 = t * 4;
    if (e0 >= E_EDGES) return;
    int4 r = *(const int4*)&ei[e0];
    int4 c = *(const int4*)&ei[E_EDGES + e0];
    float4 w = *(const float4*)&ew[e0];
    atomicAdd(&deg[r.x], w.x);
    atomicAdd(&deg[r.y], w.y);
    atomicAdd(&deg[r.z], w.z);
    atomicAdd(&deg[r.w], w.w);
    atomicAdd(&cnt[c.x], 1);
    atomicAdd(&cnt[c.y], 1);
    atomicAdd(&cnt[c.z], 1);
    atomicAdd(&cnt[c.w], 1);
}

__global__ __launch_bounds__(256) void k_dinv(float* deg) {
    int i = blockIdx.x * 256 + threadIdx.x;
    if (i < N_NODES) deg[i] = 1.0f / sqrtf(deg[i]);
}

__global__ __launch_bounds__(256) void k_scan1(const int* __restrict__ cnt,
                                               int* ptrTmp, int* bsum) {
    __shared__ int s[256];
    int t = threadIdx.x;
    int i = blockIdx.x * 256 + t;
    int v = (i < N_NODES) ? cnt[i] : 0;
    s[t] = v; __syncthreads();
    for (int off = 1; off < 256; off <<= 1) {
        int x = s[t]; int y = (t >= off) ? s[t - off] : 0;
        __syncthreads();
        s[t] = x + y; __syncthreads();
    }
    if (i < N_NODES) ptrTmp[i] = s[t] - v;
    if (t == 255) bsum[blockIdx.x] = s[255];
}

__global__ __launch_bounds__(256) void k_scan2(const int* __restrict__ bsum, int* boff) {
    __shared__ int s[256];
    int t = threadIdx.x;
    int v = (t < SCAN_BLKS) ? bsum[t] : 0;
    s[t] = v; __syncthreads();
    for (int off = 1; off < 256; off <<= 1) {
        int x = s[t]; int y = (t >= off) ? s[t - off] : 0;
        __syncthreads();
        s[t] = x + y; __syncthreads();
    }
    if (t < SCAN_BLKS) boff[t] = s[t] - v;
}

__global__ __launch_bounds__(256) void k_scan3(const int* __restrict__ ptrTmp,
                                               const int* __restrict__ boff, int* ptr) {
    int i = blockIdx.x * 256 + threadIdx.x;
    if (i < N_NODES) ptr[i] = ptrTmp[i] + boff[blockIdx.x];
    if (i == 0) ptr[N_NODES] = E_EDGES;
}

// 4 edges per thread; packed {row, norm} 8B store
__global__ __launch_bounds__(256) void k_scatter(const int* __restrict__ ei,
                                                 const float* __restrict__ ew,
                                                 const float* __restrict__ dinv,
                                                 const int* __restrict__ ptr,
                                                 int* fill, int2* __restrict__ spack) {
    int t = blockIdx.x * 256 + threadIdx.x;
    int e0 = t * 4;
    if (e0 >= E_EDGES) return;
    int4 r = *(const int4*)&ei[e0];
    int4 c = *(const int4*)&ei[E_EDGES + e0];
    float4 w = *(const float4*)&ew[e0];
#pragma unroll
    for (int j = 0; j < 4; ++j) {
        int rr = (j == 0) ? r.x : (j == 1) ? r.y : (j == 2) ? r.z : r.w;
        int cc = (j == 0) ? c.x : (j == 1) ? c.y : (j == 2) ? c.z : c.w;
        float wwv = (j == 0) ? w.x : (j == 1) ? w.y : (j == 2) ? w.z : w.w;
        int pos = ptr[cc] + atomicAdd(&fill[cc], 1);
        float nm = dinv[rr] * wwv * dinv[cc];
        int2 m; m.x = rr; m.y = __float_as_int(nm);
        spack[pos] = m;
    }
}

// ---------------- weight convert + transpose + residual fold ----------------
// layer weights become W' = beta*W + diagC*I, stored bf16 transposed [C][R]

__global__ __launch_bounds__(256) void k_convert_w(
    const float* __restrict__ w_in, const float* __restrict__ ws1,
    const float* __restrict__ ws2, const float* __restrict__ w_out,
    ushort* wt_in, ushort* wt1, ushort* wt2, ushort* wt_out) {
    __shared__ float tile[128][129];
    int b = blockIdx.x;
    const float* src; ushort* dst; int R = 128, C = 128;
    float scale = 1.f, diag = 0.f;
    if (b == 0) { src = w_in; dst = wt_in; }
    else if (b <= 16) {
        int i = b - 1;
        float beta = logf(LAMDA_C / (float)(i + 1) + 1.0f);
        scale = beta; diag = (1.f - beta) * (1.f - ALPHA_C);
        src = ws1 + (size_t)i * 16384; dst = wt1 + (size_t)i * 16384;
    } else if (b <= 32) {
        int i = b - 17;
        float beta = logf(LAMDA_C / (float)(i + 1) + 1.0f);
        scale = beta; diag = (1.f - beta) * ALPHA_C;
        src = ws2 + (size_t)i * 16384; dst = wt2 + (size_t)i * 16384;
    } else { src = w_out; dst = wt_out; C = 64; }
    for (int idx = threadIdx.x; idx < R * C; idx += 256) {
        int k = idx / C, n = idx % C;
        tile[k][n] = src[idx] * scale + ((k == n) ? diag : 0.f);
    }
    __syncthreads();
    for (int idx = threadIdx.x; idx < R * C; idx += 256) {
        int n = idx / R, k = idx % R;
        dst[idx] = f2bf(tile[k][n]);
    }
}

// ---------------- x convert (f32 -> bf16, zero-pad rows) ----------------

__global__ __launch_bounds__(256) void k_convert_x(const float* __restrict__ x,
                                                   ushort* __restrict__ xb) {
    int c8 = blockIdx.x * 256 + threadIdx.x;
    if (c8 >= N_PAD * (HDIM / 8)) return;
    int row = c8 / (HDIM / 8);
    short8 o;
    if (row < N_NODES) {
        const float4 f0 = *(const float4*)&x[(size_t)c8 * 8];
        const float4 f1 = *(const float4*)&x[(size_t)c8 * 8 + 4];
        o[0] = (short)f2bf(f0.x); o[1] = (short)f2bf(f0.y);
        o[2] = (short)f2bf(f0.z); o[3] = (short)f2bf(f0.w);
        o[4] = (short)f2bf(f1.x); o[5] = (short)f2bf(f1.y);
        o[6] = (short)f2bf(f1.z); o[7] = (short)f2bf(f1.w);
    } else {
        o = (short8){0, 0, 0, 0, 0, 0, 0, 0};
    }
    *(short8*)&xb[(size_t)c8 * 8] = o;
}

// ---------------- input GEMM: h = h0 = relu(xb @ W + bias) ----------------

__global__ __launch_bounds__(256) void k_gemm_in(
    const ushort* __restrict__ A, const ushort* __restrict__ W,
    const float* __restrict__ bias, ushort* __restrict__ O0, ushort* __restrict__ O1) {
    const int tid = threadIdx.x;
    const int wid = tid >> 6, l = tid & 63;
    const int wm = wid >> 1, wn = wid & 1;
    const int lr = l & 15, lk = l >> 4;
    const int row0 = blockIdx.x * 128 + wm * 64;
    const int col0 = wn * 64;

    short8 a[4][4], b[4][4];
#pragma unroll
    for (int m = 0; m < 4; ++m)
#pragma unroll
        for (int k = 0; k < 4; ++k)
            a[m][k] = *(const short8*)&A[(size_t)(row0 + m * 16 + lr) * HDIM + k * 32 + lk * 8];
#pragma unroll
    for (int n = 0; n < 4; ++n)
#pragma unroll
        for (int k = 0; k < 4; ++k)
            b[n][k] = *(const short8*)&W[(size_t)(col0 + n * 16 + lr) * HDIM + k * 32 + lk * 8];

    f32x4 acc[4][4];
#pragma unroll
    for (int m = 0; m < 4; ++m)
#pragma unroll
        for (int n = 0; n < 4; ++n) acc[m][n] = (f32x4){0.f, 0.f, 0.f, 0.f};
#pragma unroll
    for (int k = 0; k < 4; ++k)
#pragma unroll
        for (int m = 0; m < 4; ++m)
#pragma unroll
            for (int n = 0; n < 4; ++n)
                acc[m][n] = __builtin_amdgcn_mfma_f32_16x16x32_bf16(a[m][k], b[n][k], acc[m][n], 0, 0, 0);

    float bv[4];
#pragma unroll
    for (int n = 0; n < 4; ++n) bv[n] = bias[col0 + n * 16 + lr];
#pragma unroll
    for (int m = 0; m < 4; ++m) {
        const int rb = row0 + m * 16 + lk * 4;
#pragma unroll
        for (int j = 0; j < 4; ++j) {
            const size_t ro = (size_t)(rb + j) * HDIM;
#pragma unroll
            for (int n = 0; n < 4; ++n) {
                const int c = col0 + n * 16 + lr;
                float v = fmaxf(acc[m][n][j] + bv[n], 0.f);
                ushort u = f2bf(v);
                O0[ro + c] = u;
                O1[ro + c] = u;
            }
        }
    }
}

// ---------------- fused layer GEMMs: O = A @ W'  (residual folded into W') ----------------

__global__ __launch_bounds__(256) void k_gemm2(
    const ushort* __restrict__ A0, const ushort* __restrict__ A1,
    const ushort* __restrict__ W0, const ushort* __restrict__ W1,
    ushort* __restrict__ O0, ushort* __restrict__ O1) {
    const int y = blockIdx.y;
    const ushort* __restrict__ A = y ? A1 : A0;
    const ushort* __restrict__ W = y ? W1 : W0;
    ushort* __restrict__ O = y ? O1 : O0;
    const int tid = threadIdx.x;
    const int wid = tid >> 6, l = tid & 63;
    const int wm = wid >> 1, wn = wid & 1;
    const int lr = l & 15, lk = l >> 4;
    const int row0 = blockIdx.x * 128 + wm * 64;
    const int col0 = wn * 64;

    short8 a[4][4], b[4][4];
#pragma unroll
    for (int m = 0; m < 4; ++m)
#pragma unroll
        for (int k = 0; k < 4; ++k)
            a[m][k] = *(const short8*)&A[(size_t)(row0 + m * 16 + lr) * HDIM + k * 32 + lk * 8];
#pragma unroll
    for (int n = 0; n < 4; ++n)
#pragma unroll
        for (int k = 0; k < 4; ++k)
            b[n][k] = *(const short8*)&W[(size_t)(col0 + n * 16 + lr) * HDIM + k * 32 + lk * 8];

    f32x4 acc[4][4];
#pragma unroll
    for (int m = 0; m < 4; ++m)
#pragma unroll
        for (int n = 0; n < 4; ++n) acc[m][n] = (f32x4){0.f, 0.f, 0.f, 0.f};
#pragma unroll
    for (int k = 0; k < 4; ++k)
#pragma unroll
        for (int m = 0; m < 4; ++m)
#pragma unroll
            for (int n = 0; n < 4; ++n)
                acc[m][n] = __builtin_amdgcn_mfma_f32_16x16x32_bf16(a[m][k], b[n][k], acc[m][n], 0, 0, 0);

#pragma unroll
    for (int m = 0; m < 4; ++m) {
        const int rb = row0 + m * 16 + lk * 4;
#pragma unroll
        for (int j = 0; j < 4; ++j) {
            const size_t ro = (size_t)(rb + j) * HDIM;
#pragma unroll
            for (int n = 0; n < 4; ++n)
                O[ro + col0 + n * 16 + lr] = f2bf(acc[m][n][j]);
        }
    }
}

// ---------------- aggregation v2: wave per node, quarter-wave per edge ----------------
// 4 edges in flight per wave; 16B/lane gathers; packed metadata

__global__ __launch_bounds__(256) void k_aggregate(
    const ushort* __restrict__ support, const ushort* __restrict__ initial,
    const float* __restrict__ dinv, const int* __restrict__ ptr,
    const int2* __restrict__ spack, ushort* __restrict__ hout) {
    int v = blockIdx.x * 4 + (threadIdx.x >> 6);
    int l = threadIdx.x & 63;
    int q = l >> 4, i = l & 15;
    if (v >= N_NODES) return;
    int beg = ptr[v], end = ptr[v + 1];

    float acc[8];
#pragma unroll
    for (int d = 0; d < 8; ++d) acc[d] = 0.f;

    for (int base = beg; base < end; base += 64) {
        int cnt = end - base; if (cnt > 64) cnt = 64;
        int2 meta = make_int2(0, 0);
        if (base + l < end) meta = spack[base + l];
        for (int j = 0; j < cnt; j += 4) {
            int idx = j + q;
            int rr = __shfl(meta.x, idx);
            int nb = __shfl(meta.y, idx);
            if (idx < cnt) {
                float nn = __int_as_float(nb);
                short8 sv = *(const short8*)&support[(size_t)rr * HDIM + i * 8];
#pragma unroll
                for (int d = 0; d < 8; ++d)
                    acc[d] = fmaf(nn, bf2f((ushort)sv[d]), acc[d]);
            }
        }
    }
#pragma unroll
    for (int d = 0; d < 8; ++d) {
        acc[d] += __shfl_xor(acc[d], 16);
        acc[d] += __shfl_xor(acc[d], 32);
    }
    if (q == 0) {
        float dv = dinv[v];
        float dv2 = dv * dv;
        short8 s0 = *(const short8*)&support[(size_t)v * HDIM + i * 8];
        short8 ini = *(const short8*)&initial[(size_t)v * HDIM + i * 8];
        short8 o;
#pragma unroll
        for (int d = 0; d < 8; ++d) {
            float x = acc[d] + dv2 * bf2f((ushort)s0[d]) + bf2f((ushort)ini[d]);
            o[d] = (short)f2bf(fmaxf(x, 0.f));
        }
        *(short8*)&hout[(size_t)v * HDIM + i * 8] = o;
    }
}

// ---------------- output GEMM + fused bias + log_softmax ----------------

__global__ __launch_bounds__(256) void k_gemm_out(
    const ushort* __restrict__ A, const ushort* __restrict__ W,
    const float* __restrict__ bias, float* __restrict__ out) {
    const int tid = threadIdx.x;
    const int wid = tid >> 6, l = tid & 63;
    const int lr = l & 15, lk = l >> 4;
    const int row0 = blockIdx.x * 128 + wid * 32;

    short8 a[2][4], b[4][4];
#pragma unroll
    for (int m = 0; m < 2; ++m)
#pragma unroll
        for (int k = 0; k < 4; ++k)
            a[m][k] = *(const short8*)&A[(size_t)(row0 + m * 16 + lr) * HDIM + k * 32 + lk * 8];
#pragma unroll
    for (int n = 0; n < 4; ++n)
#pragma unroll
        for (int k = 0; k < 4; ++k)
            b[n][k] = *(const short8*)&W[(size_t)(n * 16 + lr) * HDIM + k * 32 + lk * 8];

    f32x4 acc[2][4];
#pragma unroll
    for (int m = 0; m < 2; ++m)
#pragma unroll
        for (int n = 0; n < 4; ++n) acc[m][n] = (f32x4){0.f, 0.f, 0.f, 0.f};
#pragma unroll
    for (int k = 0; k < 4; ++k)
#pragma unroll
        for (int m = 0; m < 2; ++m)
#pragma unroll
            for (int n = 0; n < 4; ++n)
                acc[m][n] = __builtin_amdgcn_mfma_f32_16x16x32_bf16(a[m][k], b[n][k], acc[m][n], 0, 0, 0);

    float bv[4];
#pragma unroll
    for (int n = 0; n < 4; ++n) bv[n] = bias[n * 16 + lr];

#pragma unroll
    for (int m = 0; m < 2; ++m) {
#pragma unroll
        for (int j = 0; j < 4; ++j) {
            float z[4];
#pragma unroll
            for (int n = 0; n < 4; ++n) z[n] = acc[m][n][j] + bv[n];
            float mx = fmaxf(fmaxf(z[0], z[1]), fmaxf(z[2], z[3]));
#pragma unroll
            for (int off = 1; off < 16; off <<= 1) mx = fmaxf(mx, __shfl_xor(mx, off));
            float s = 0.f;
#pragma unroll
            for (int n = 0; n < 4; ++n) s += expf(z[n] - mx);
#pragma unroll
            for (int off = 1; off < 16; off <<= 1) s += __shfl_xor(s, off);
            float lg = mx + logf(s);
            int r = row0 + m * 16 + lk * 4 + j;
            if (r < N_NODES) {
#pragma unroll
                for (int n = 0; n < 4; ++n)
                    out[(size_t)r * COUT + n * 16 + lr] = z[n] - lg;
            }
        }
    }
}

// ---------------- launch ----------------

extern "C" void kernel_launch(void* const* d_in, const int* in_sizes, int n_in,
                              void* d_out, int out_size, void* d_ws, size_t ws_size,
                              hipStream_t stream) {
    const float* x = (const float*)d_in[0];
    const int* ei = (const int*)d_in[1];
    const float* ew = (const float*)d_in[2];
    const float* w_in = (const float*)d_in[3];
    const float* b_in = (const float*)d_in[4];
    const float* ws1 = (const float*)d_in[5];
    const float* ws2 = (const float*)d_in[6];
    const float* w_out = (const float*)d_in[7];
    const float* b_out = (const float*)d_in[8];
    float* out = (float*)d_out;

    char* p = (char*)d_ws;
    auto alloc = [&](size_t bytes) {
        void* r = (void*)p;
        p += (bytes + 255) & ~(size_t)255;
        return r;
    };
    float* dinv = (float*)alloc(N_NODES * 4);
    int* cnt = (int*)alloc(N_NODES * 4);
    int* ptrTmp = (int*)alloc(N_NODES * 4);
    int* bsum = (int*)alloc(256 * 4);
    int* boff = (int*)alloc(256 * 4);
    int* ptr = (int*)alloc((N_NODES + 1) * 4);
    int* fill = (int*)alloc(N_NODES * 4);
    int2* spack = (int2*)alloc((size_t)E_EDGES * 8);
    ushort* xb = (ushort*)alloc((size_t)N_PAD * HDIM * 2);
    ushort* h = (ushort*)alloc((size_t)N_PAD * HDIM * 2);
    ushort* h0 = (ushort*)alloc((size_t)N_PAD * HDIM * 2);
    ushort* support = (ushort*)alloc((size_t)N_PAD * HDIM * 2);
    ushort* init = (ushort*)alloc((size_t)N_PAD * HDIM * 2);
    ushort* wt_in = (ushort*)alloc(128 * 128 * 2);
    ushort* wt1 = (ushort*)alloc((size_t)NLAYERS * 128 * 128 * 2);
    ushort* wt2 = (ushort*)alloc((size_t)NLAYERS * 128 * 128 * 2);
    ushort* wt_out = (ushort*)alloc(64 * 128 * 2);

    const int ge4 = (E_EDGES / 4 + 255) / 256;  // 625
    k_init<<<SCAN_BLKS, 256, 0, stream>>>(dinv, cnt, fill);
    k_edge<<<ge4, 256, 0, stream>>>(ei, ew, dinv, cnt);
    k_dinv<<<SCAN_BLKS, 256, 0, stream>>>(dinv);
    k_scan1<<<SCAN_BLKS, 256, 0, stream>>>(cnt, ptrTmp, bsum);
    k_scan2<<<1, 256, 0, stream>>>(bsum, boff);
    k_scan3<<<SCAN_BLKS, 256, 0, stream>>>(ptrTmp, boff, ptr);
    k_scatter<<<ge4, 256, 0, stream>>>(ei, ew, dinv, ptr, fill, spack);

    k_convert_w<<<34, 256, 0, stream>>>(w_in, ws1, ws2, w_out, wt_in, wt1, wt2, wt_out);
    k_convert_x<<<(N_PAD * (HDIM / 8) + 255) / 256, 256, 0, stream>>>(x, xb);

    const int gb = N_PAD / 128;  // 391
    k_gemm_in<<<gb, 256, 0, stream>>>(xb, wt_in, b_in, h, h0);

    for (int i = 0; i < NLAYERS; ++i) {
        k_gemm2<<<dim3(gb, 2), 256, 0, stream>>>(h, h0,
                                                 wt1 + (size_t)i * 16384,
                                                 wt2 + (size_t)i * 16384,
                                                 support, init);
        k_aggregate<<<(N_NODES + 3) / 4, 256, 0, stream>>>(support, init, dinv, ptr,
                                                           spack, h);
    }

    k_gemm_out<<<gb, 256, 0, stream>>>(h, wt_out, b_out, out);
}